// Round 18
// baseline (64.562 us; speedup 1.0000x reference)
//
#include <hip/hip_runtime.h>

#define NB 2
#define NC 6
#define NV 50000
#define ND 384
#define NF 64
#define NP 100000
#define NM 1369
#define NROW (NB*NV)   // 100000
#define NT (NB*NC*NM)  // 16428 tokens
#define TILE 32        // voxels per block -> 3125 blocks

typedef __attribute__((ext_vector_type(8))) short bf8_t;   // 8 bf16 (4 VGPRs)
typedef __attribute__((ext_vector_type(4))) float f4_t;    // 4 fp32 acc
typedef unsigned long long u64;

// RNE float->bf16 (inputs finite)
__device__ inline unsigned short f2bf(float x) {
    unsigned u = __builtin_bit_cast(unsigned, x);
    u += 0x7fffu + ((u >> 16) & 1u);
    return (unsigned short)(u >> 16);
}
__device__ inline unsigned pack2bf(float lo, float hi) {
    return (unsigned)f2bf(lo) | ((unsigned)f2bf(hi) << 16);
}
__device__ inline float bflo(unsigned u) { return __builtin_bit_cast(float, u << 16); }
__device__ inline float bfhi(unsigned u) { return __builtin_bit_cast(float, u & 0xffff0000u); }

// fp32 projection matching numpy einsum exactly (verified r8-r17: passes)
__device__ inline void proj_one(const float* __restrict__ E,
                                const float* __restrict__ Km,
                                float x, float y, float z,
                                float Ws, float Hs, float sx, float sy,
                                bool& valid, int& flat)
{
#pragma clang fp contract(off)
    const float X = ((E[0]*x + E[1]*y) + E[2]*z) + E[3];
    const float Y = ((E[4]*x + E[5]*y) + E[6]*z) + E[7];
    const float Z = ((E[8]*x + E[9]*y) + E[10]*z) + E[11];
    const float p0 = (Km[0]*X + Km[1]*Y) + Km[2]*Z;
    const float p1 = (Km[3]*X + Km[4]*Y) + Km[5]*Z;
    const float p2 = (Km[6]*X + Km[7]*Y) + Km[8]*Z;
    const float den = fmaxf(p2, 1e-12f);
    const float u = p0 / den;
    const float v = p1 / den;
    valid = (Z > 0.0f) & (u >= 0.0f) & (u < Ws) & (v >= 0.0f) & (v < Hs);
    const float us = u * sx;
    const float vs = v * sy;
    int px = (int)(us / 14.0f);
    int py = (int)(vs / 14.0f);
    px = px < 0 ? 0 : (px > 36 ? 36 : px);
    py = py < 0 ? 0 : (py > 36 ? 36 : py);
    flat = py*37 + px;
}

// Merged prepack: W1 (448x256), W2 (256x64), W3 (64x16) -> fragment-ordered bf16.
__global__ __launch_bounds__(256) void pack_all(
    const float* __restrict__ W1, const float* __restrict__ W2,
    const float* __restrict__ W3,
    unsigned short* __restrict__ o1, unsigned short* __restrict__ o2,
    unsigned short* __restrict__ o3)
{
    const int blk = blockIdx.x;
    if (blk < 448) {              // W1
        const int t = blk*256 + threadIdx.x;          // < 448*256
        const int k = t >> 8, n = t & 255;
        const int kc = k >> 5, g = (k >> 3) & 3, i = k & 7;
        const int w = n >> 6, nf = (n >> 4) & 3, m = n & 15;
        o1[(((kc*16 + w*4 + nf)*64 + g*16 + m) << 3) + i] = f2bf(W1[k*256 + n]);
    } else if (blk < 512) {       // W2
        const int t = (blk - 448)*256 + threadIdx.x;  // < 256*64
        const int k = t >> 6, n = t & 63;
        const int kc = k >> 5, g = (k >> 3) & 3, i = k & 7;
        const int nf = n >> 4, m = n & 15;
        o2[(((kc*4 + nf)*64 + g*16 + m) << 3) + i] = f2bf(W2[k*64 + n]);
    } else {                      // W3
        const int t = (blk - 512)*256 + threadIdx.x;  // < 64*16
        const int k = t >> 4, n = t & 15;
        const int kc = k >> 5, g = (k >> 3) & 3, i = k & 7;
        o3[((kc*64 + g*16 + n) << 3) + i] = f2bf(W3[k*16 + n]);
    }
}

// ptok: T[t][n] = bf16( patch[t][:] @ W1[64:448][n] ) for all 16428 tokens.
// LDS-staged coalesced patch loads (verified r13: -10us vs strided).
__global__ __launch_bounds__(256) void ptok_kernel(
    const float* __restrict__ patch,
    const unsigned short* __restrict__ w1p_,
    unsigned short* __restrict__ T)
{
    __shared__ __align__(16) unsigned short sA[32*408];

    const int tid  = threadIdx.x;
    const int lane = tid & 63;
    const int w    = __builtin_amdgcn_readfirstlane(tid >> 6);  // wave-uniform -> SGPR
    const int mrow = lane & 15;
    const int kg   = lane >> 4;
    const int rbase = blockIdx.x * 32;

    unsigned* sA32 = (unsigned*)sA;
    #pragma unroll
    for (int i = 0; i < 8; ++i) {
        const int r = w + 4*i;
        int row = rbase + r;
        row = row < NT ? row : NT - 1;
        const float2* src = (const float2*)(patch + (size_t)row*ND);
        #pragma unroll
        for (int c = 0; c < 3; ++c) {
            const float2 v = src[c*64 + lane];
            sA32[r*204 + c*64 + lane] = pack2bf(v.x, v.y);
        }
    }
    __syncthreads();

    const bf8_t* w1p = (const bf8_t*)w1p_;
    const f4_t zero = {0.f, 0.f, 0.f, 0.f};
    f4_t acc[2][4];
    #pragma unroll
    for (int a = 0; a < 2; ++a)
        #pragma unroll
        for (int q = 0; q < 4; ++q) acc[a][q] = zero;

    for (int j = 0; j < 12; ++j) {
        const bf8_t a0 = *(const bf8_t*)&sA[ mrow      *408 + j*32 + kg*8];
        const bf8_t a1 = *(const bf8_t*)&sA[(mrow + 16)*408 + j*32 + kg*8];
        const bf8_t* bp = w1p + (size_t)(((j+2)*16 + w*4)*64 + lane);
        #pragma unroll
        for (int nf = 0; nf < 4; ++nf) {
            const bf8_t bfr = bp[nf*64];
            acc[0][nf] = __builtin_amdgcn_mfma_f32_16x16x32_bf16(a0, bfr, acc[0][nf], 0, 0, 0);
            acc[1][nf] = __builtin_amdgcn_mfma_f32_16x16x32_bf16(a1, bfr, acc[1][nf], 0, 0, 0);
        }
    }
    #pragma unroll
    for (int nf = 0; nf < 4; ++nf)
        #pragma unroll
        for (int mf = 0; mf < 2; ++mf)
            #pragma unroll
            for (int r = 0; r < 4; ++r) {
                const int trow = rbase + mf*16 + kg*4 + r;
                if (trow < NT)
                    T[(size_t)trow*256 + w*64 + nf*16 + mrow] = f2bf(acc[mf][nf][r]);
            }
}

// Fused: A1 projection -> miniGEMM -> A2 gather with forced 12-load asm batch
// (scalar saddr, single vmcnt(0)) + scalar-branched consumption -> GEMM2 -> GEMM3.
// LDS: sVP 16,896B + sVF 4,608B + sFlat 768B = 22,272B -> 7 blocks/CU.
__global__ __launch_bounds__(256, 7) void fuse_mlp_kernel(
    const float* __restrict__ vfeat,   // (B,V,F)
    const float* __restrict__ vcoord,  // (B,V,3)
    const float* __restrict__ imsz,    // (B,2)
    const float* __restrict__ intr,    // (B,C,3,3)
    const float* __restrict__ extr,    // (B,C,4,4)
    const float* __restrict__ b1,
    const float* __restrict__ b2,
    const float* __restrict__ b3,
    const unsigned short* __restrict__ w1p_,  // packed bf16 W1 (kc 0..1 used)
    const unsigned short* __restrict__ w2p_,
    const unsigned short* __restrict__ w3p_,
    const unsigned short* __restrict__ T,     // (16428,256) bf16
    float* __restrict__ scores)        // ws: (B*V,16)
{
    __shared__ __align__(16) unsigned short sVP[TILE*264];  // vpart+b1, then h1 bf16
    __shared__ __align__(16) unsigned short sVF[TILE*72];   // vfeat bf16; later h2 bf16
    __shared__ int sFlat[NC*TILE];

    const int tid  = threadIdx.x;
    const int base = blockIdx.x * TILE;
    const int lane = tid & 63;
    const int w    = __builtin_amdgcn_readfirstlane(tid >> 6);  // wave-uniform -> SGPR
    const int mrow = lane & 15;
    const int kg   = lane >> 4;

    // ---------- load vfeat -> sVF bf16 (float2-vectorized, coalesced) ----------
    #pragma unroll
    for (int i = 0; i < 4; ++i) {
        const int e = tid + 256*i;          // < 1024 float2 elements
        const int r = e >> 5, c2 = e & 31;
        const float2 v = *(const float2*)&vfeat[(size_t)(base + r)*NF + c2*2];
        *(unsigned*)&sVF[r*72 + c2*2] = pack2bf(v.x, v.y);
    }

    // ---------- A1: pair-parallel projection ----------
    if (tid < NC*TILE) {
        const int r = tid & 31, c = tid >> 5;
        const int n = base + r;
        const int b = n / NV;
        const float x = vcoord[(size_t)n*3+0];
        const float y = vcoord[(size_t)n*3+1];
        const float z = vcoord[(size_t)n*3+2];
        const float Hs = imsz[b*2+0];
        const float Ws = imsz[b*2+1];
        const float sx = 518.0f / fmaxf(Ws, 1e-6f);
        const float sy = 518.0f / fmaxf(Hs, 1e-6f);
        const float* E  = extr + (size_t)(b*NC + c)*16;
        const float* Km = intr + (size_t)(b*NC + c)*9;
        bool valid; int flat;
        proj_one(E, Km, x, y, z, Ws, Hs, sx, sy, valid, flat);
        sFlat[c*TILE + r] = valid ? flat : -1;
    }
    __syncthreads();

    // ---------- miniGEMM: vpart = vfeat(32x64) @ W1a(64x256) + b1 (NO relu) ----------
    const bf8_t* w1p = (const bf8_t*)w1p_;
    const f4_t zero = {0.f, 0.f, 0.f, 0.f};
    f4_t acc1[2][4];
    #pragma unroll
    for (int a = 0; a < 2; ++a)
        #pragma unroll
        for (int q = 0; q < 4; ++q) acc1[a][q] = zero;
    #pragma unroll
    for (int kc = 0; kc < 2; ++kc) {
        const bf8_t a0 = *(const bf8_t*)&sVF[ mrow      *72 + kc*32 + kg*8];
        const bf8_t a1 = *(const bf8_t*)&sVF[(mrow + 16)*72 + kc*32 + kg*8];
        const bf8_t* bp = w1p + (size_t)((kc*16 + w*4)*64 + lane);
        #pragma unroll
        for (int nf = 0; nf < 4; ++nf) {
            const bf8_t bfr = bp[nf*64];
            acc1[0][nf] = __builtin_amdgcn_mfma_f32_16x16x32_bf16(a0, bfr, acc1[0][nf], 0, 0, 0);
            acc1[1][nf] = __builtin_amdgcn_mfma_f32_16x16x32_bf16(a1, bfr, acc1[1][nf], 0, 0, 0);
        }
    }
    #pragma unroll
    for (int nf = 0; nf < 4; ++nf) {
        const float bb = b1[w*64 + nf*16 + mrow];
        #pragma unroll
        for (int mf = 0; mf < 2; ++mf)
            #pragma unroll
            for (int r = 0; r < 4; ++r)
                sVP[(mf*16 + kg*4 + r)*264 + w*64 + nf*16 + mrow] = f2bf(acc1[mf][nf][r] + bb);
    }
    __syncthreads();

    // ---------- A2: paired gather; asm-forced 12-load batch, one vmcnt(0) ----------
    const int voff = lane << 3;   // byte offset within T row (lane*8)
    #pragma unroll
    for (int t4 = 0; t4 < 4; ++t4) {
        const int r0 = w + 8*t4, r1 = r0 + 4;                 // SGPR
        const int cb0 = ((base + r0) / NV) * NC;              // SGPR
        const int cb1 = ((base + r1) / NV) * NC;
        const int f00 = __builtin_amdgcn_readfirstlane(sFlat[0*TILE + r0]);
        const int f01 = __builtin_amdgcn_readfirstlane(sFlat[1*TILE + r0]);
        const int f02 = __builtin_amdgcn_readfirstlane(sFlat[2*TILE + r0]);
        const int f03 = __builtin_amdgcn_readfirstlane(sFlat[3*TILE + r0]);
        const int f04 = __builtin_amdgcn_readfirstlane(sFlat[4*TILE + r0]);
        const int f05 = __builtin_amdgcn_readfirstlane(sFlat[5*TILE + r0]);
        const int f10 = __builtin_amdgcn_readfirstlane(sFlat[0*TILE + r1]);
        const int f11 = __builtin_amdgcn_readfirstlane(sFlat[1*TILE + r1]);
        const int f12 = __builtin_amdgcn_readfirstlane(sFlat[2*TILE + r1]);
        const int f13 = __builtin_amdgcn_readfirstlane(sFlat[3*TILE + r1]);
        const int f14 = __builtin_amdgcn_readfirstlane(sFlat[4*TILE + r1]);
        const int f15 = __builtin_amdgcn_readfirstlane(sFlat[5*TILE + r1]);
        #define TROW(CB,CC,F) (T + ((size_t)((CB)+(CC))*NM + ((F)<0?0:(F)))*256)
        const unsigned short* rp00 = TROW(cb0,0,f00);
        const unsigned short* rp01 = TROW(cb0,1,f01);
        const unsigned short* rp02 = TROW(cb0,2,f02);
        const unsigned short* rp03 = TROW(cb0,3,f03);
        const unsigned short* rp04 = TROW(cb0,4,f04);
        const unsigned short* rp05 = TROW(cb0,5,f05);
        const unsigned short* rp10 = TROW(cb1,0,f10);
        const unsigned short* rp11 = TROW(cb1,1,f11);
        const unsigned short* rp12 = TROW(cb1,2,f12);
        const unsigned short* rp13 = TROW(cb1,3,f13);
        const unsigned short* rp14 = TROW(cb1,4,f14);
        const unsigned short* rp15 = TROW(cb1,5,f15);
        #undef TROW
        u64 q00, q01, q02, q03, q04, q05, q10, q11, q12, q13, q14, q15;
        asm volatile(
            "global_load_dwordx2 %0, %12, %13\n\t"
            "global_load_dwordx2 %1, %12, %14\n\t"
            "global_load_dwordx2 %2, %12, %15\n\t"
            "global_load_dwordx2 %3, %12, %16\n\t"
            "global_load_dwordx2 %4, %12, %17\n\t"
            "global_load_dwordx2 %5, %12, %18\n\t"
            "global_load_dwordx2 %6, %12, %19\n\t"
            "global_load_dwordx2 %7, %12, %20\n\t"
            "global_load_dwordx2 %8, %12, %21\n\t"
            "global_load_dwordx2 %9, %12, %22\n\t"
            "global_load_dwordx2 %10, %12, %23\n\t"
            "global_load_dwordx2 %11, %12, %24\n\t"
            "s_waitcnt vmcnt(0)"
            : "=&v"(q00), "=&v"(q01), "=&v"(q02), "=&v"(q03), "=&v"(q04), "=&v"(q05),
              "=&v"(q10), "=&v"(q11), "=&v"(q12), "=&v"(q13), "=&v"(q14), "=&v"(q15)
            : "v"(voff),
              "s"(rp00), "s"(rp01), "s"(rp02), "s"(rp03), "s"(rp04), "s"(rp05),
              "s"(rp10), "s"(rp11), "s"(rp12), "s"(rp13), "s"(rp14), "s"(rp15));
        float A0=0.f, A1=0.f, A2=0.f, A3=0.f; int cnt0 = 0;
        float B0=0.f, B1=0.f, B2=0.f, B3=0.f; int cnt1 = 0;
        // consume in r16's exact order/conditions -> bit-identical sums
        #define ACCA(Q,F) if ((F) >= 0) { \
            A0 += bflo((unsigned)(Q));          A1 += bfhi((unsigned)(Q)); \
            A2 += bflo((unsigned)((Q) >> 32));  A3 += bfhi((unsigned)((Q) >> 32)); ++cnt0; }
        #define ACCB(Q,F) if ((F) >= 0) { \
            B0 += bflo((unsigned)(Q));          B1 += bfhi((unsigned)(Q)); \
            B2 += bflo((unsigned)((Q) >> 32));  B3 += bfhi((unsigned)((Q) >> 32)); ++cnt1; }
        ACCA(q00,f00) ACCA(q01,f01) ACCA(q02,f02)
        ACCA(q03,f03) ACCA(q04,f04) ACCA(q05,f05)
        ACCB(q10,f10) ACCB(q11,f11) ACCB(q12,f12)
        ACCB(q13,f13) ACCB(q14,f14) ACCB(q15,f15)
        #undef ACCA
        #undef ACCB
        const float inv0 = 1.0f / fmaxf((float)cnt0, 1.0f);
        const float inv1 = 1.0f / fmaxf((float)cnt1, 1.0f);
        {
            const uint2 vp = *(uint2*)&sVP[r0*264 + lane*4];
            const float h0 = fmaxf(A0*inv0 + bflo(vp.x), 0.f);
            const float h1v = fmaxf(A1*inv0 + bfhi(vp.x), 0.f);
            const float h2v = fmaxf(A2*inv0 + bflo(vp.y), 0.f);
            const float h3 = fmaxf(A3*inv0 + bfhi(vp.y), 0.f);
            uint2 o; o.x = pack2bf(h0, h1v); o.y = pack2bf(h2v, h3);
            *(uint2*)&sVP[r0*264 + lane*4] = o;
        }
        {
            const uint2 vp = *(uint2*)&sVP[r1*264 + lane*4];
            const float h0 = fmaxf(B0*inv1 + bflo(vp.x), 0.f);
            const float h1v = fmaxf(B1*inv1 + bfhi(vp.x), 0.f);
            const float h2v = fmaxf(B2*inv1 + bflo(vp.y), 0.f);
            const float h3 = fmaxf(B3*inv1 + bfhi(vp.y), 0.f);
            uint2 o; o.x = pack2bf(h0, h1v); o.y = pack2bf(h2v, h3);
            *(uint2*)&sVP[r1*264 + lane*4] = o;
        }
    }
    __syncthreads();

    // ---------- GEMM2 (MFMA): h2 = relu(h1(32x256) @ W2(256x64) + b2) ----------
    unsigned short* sH1 = sVP;
    unsigned short* sH2bf = sVF;     // overlay (sVF dead after miniGEMM)
    const bf8_t* w2p = (const bf8_t*)w2p_;
    f4_t acc2[2];
    acc2[0] = zero; acc2[1] = zero;
    for (int kc = 0; kc < 8; ++kc) {
        const bf8_t a0 = *(const bf8_t*)&sH1[ mrow      *264 + kc*32 + kg*8];
        const bf8_t a1 = *(const bf8_t*)&sH1[(mrow + 16)*264 + kc*32 + kg*8];
        const bf8_t bfr = w2p[(kc*4 + w)*64 + lane];
        acc2[0] = __builtin_amdgcn_mfma_f32_16x16x32_bf16(a0, bfr, acc2[0], 0, 0, 0);
        acc2[1] = __builtin_amdgcn_mfma_f32_16x16x32_bf16(a1, bfr, acc2[1], 0, 0, 0);
    }
    {
        const float bb = b2[w*16 + mrow];
        #pragma unroll
        for (int mf = 0; mf < 2; ++mf)
            #pragma unroll
            for (int r = 0; r < 4; ++r) {
                const float v = fmaxf(acc2[mf][r] + bb, 0.f);
                sH2bf[(mf*16 + kg*4 + r)*72 + w*16 + mrow] = f2bf(v);
            }
    }
    __syncthreads();

    // ---------- GEMM3 (MFMA, waves 0-1): scores = h2(32x64) @ W3(64x16) + b3 ----------
    if (w < 2) {
        const bf8_t* w3p = (const bf8_t*)w3p_;
        f4_t acc3 = zero;
        #pragma unroll
        for (int kc = 0; kc < 2; ++kc) {
            const bf8_t a = *(const bf8_t*)&sH2bf[(w*16 + mrow)*72 + kc*32 + kg*8];
            const bf8_t bfr = w3p[kc*64 + lane];
            acc3 = __builtin_amdgcn_mfma_f32_16x16x32_bf16(a, bfr, acc3, 0, 0, 0);
        }
        const float bb = b3[mrow];
        #pragma unroll
        for (int r = 0; r < 4; ++r)
            scores[(size_t)(base + w*16 + kg*4 + r)*16 + mrow] = acc3[r] + bb;
    }
}

// out[b,p,:] = scores[b*V + idx[b,p], :]
__global__ __launch_bounds__(256) void gather_kernel(
    const float* __restrict__ scores,
    const int* __restrict__ p2v,
    float* __restrict__ out)
{
    const int g  = blockIdx.x * 256 + threadIdx.x;  // < 800000
    const int q  = g & 3;
    const int pl = g >> 2;
    const int b  = pl / NP;
    const int idx = p2v[pl];
    const float4 val = *(const float4*)&scores[((size_t)(b*NV + idx))*16 + q*4];
    *(float4*)&out[(size_t)g*4] = val;
}

extern "C" void kernel_launch(void* const* d_in, const int* in_sizes, int n_in,
                              void* d_out, int out_size, void* d_ws, size_t ws_size,
                              hipStream_t stream) {
    const float* patch = (const float*)d_in[0];
    const float* vfeat = (const float*)d_in[1];
    const float* vcoord= (const float*)d_in[2];
    const float* imsz  = (const float*)d_in[3];
    const float* intr  = (const float*)d_in[4];
    const float* extr  = (const float*)d_in[5];
    const int*   p2v   = (const int*)d_in[6];
    const float* W1 = (const float*)d_in[7];
    const float* b1 = (const float*)d_in[8];
    const float* W2 = (const float*)d_in[9];
    const float* b2 = (const float*)d_in[10];
    const float* W3 = (const float*)d_in[11];
    const float* b3 = (const float*)d_in[12];

    float* scores = (float*)d_ws;                                        // 6,400,000 B
    unsigned short* w1pack = (unsigned short*)((char*)d_ws + 6400000);   // 229,376 B
    unsigned short* w2pack = (unsigned short*)((char*)d_ws + 6629376);   // 32,768 B
    unsigned short* w3pack = (unsigned short*)((char*)d_ws + 6662144);   // 2,048 B
    unsigned short* Tbuf   = (unsigned short*)((char*)d_ws + 6664192);   // 8,411,136 B

    pack_all<<<516, 256, 0, stream>>>(W1, W2, W3, w1pack, w2pack, w3pack);
    ptok_kernel<<<(NT + 31)/32, 256, 0, stream>>>(patch, w1pack, Tbuf);
    fuse_mlp_kernel<<<NROW/TILE, 256, 0, stream>>>(
        vfeat, vcoord, imsz, intr, extr,
        b1, b2, b3, w1pack, w2pack, w3pack, Tbuf, scores);
    gather_kernel<<<(NB*NP*4)/256, 256, 0, stream>>>(scores, p2v, (float*)d_out);
}

// Round 19
// 56.650 us; speedup vs baseline: 1.1397x; 1.1397x over previous
//
#include <hip/hip_runtime.h>

#define NB 2
#define NC 6
#define NV 50000
#define ND 384
#define NF 64
#define NP 100000
#define NM 1369
#define NROW (NB*NV)   // 100000
#define NT (NB*NC*NM)  // 16428 tokens
#define TILE 32        // voxels per block -> 3125 blocks

typedef __attribute__((ext_vector_type(8))) short bf8_t;   // 8 bf16 (4 VGPRs)
typedef __attribute__((ext_vector_type(4))) float f4_t;    // 4 fp32 acc

// RNE float->bf16 (inputs finite)
__device__ inline unsigned short f2bf(float x) {
    unsigned u = __builtin_bit_cast(unsigned, x);
    u += 0x7fffu + ((u >> 16) & 1u);
    return (unsigned short)(u >> 16);
}
__device__ inline unsigned pack2bf(float lo, float hi) {
    return (unsigned)f2bf(lo) | ((unsigned)f2bf(hi) << 16);
}
__device__ inline float bflo(unsigned u) { return __builtin_bit_cast(float, u << 16); }
__device__ inline float bfhi(unsigned u) { return __builtin_bit_cast(float, u & 0xffff0000u); }

// wave-uniform cnt (0..6) -> fp32 reciprocal of max(cnt,1); constants are the
// correctly-rounded IEEE quotients (same bits as runtime 1.0f/cnt) -> bit-exact.
__device__ inline float inv_cnt(int c) {
    return c <= 1 ? 1.0f
         : (c == 2 ? 0.5f
         : (c == 3 ? (1.0f/3.0f)
         : (c == 4 ? 0.25f
         : (c == 5 ? 0.2f : (1.0f/6.0f)))));
}

// fp32 projection matching numpy einsum exactly (verified r8-r18: passes)
__device__ inline void proj_one(const float* __restrict__ E,
                                const float* __restrict__ Km,
                                float x, float y, float z,
                                float Ws, float Hs, float sx, float sy,
                                bool& valid, int& flat)
{
#pragma clang fp contract(off)
    const float X = ((E[0]*x + E[1]*y) + E[2]*z) + E[3];
    const float Y = ((E[4]*x + E[5]*y) + E[6]*z) + E[7];
    const float Z = ((E[8]*x + E[9]*y) + E[10]*z) + E[11];
    const float p0 = (Km[0]*X + Km[1]*Y) + Km[2]*Z;
    const float p1 = (Km[3]*X + Km[4]*Y) + Km[5]*Z;
    const float p2 = (Km[6]*X + Km[7]*Y) + Km[8]*Z;
    const float den = fmaxf(p2, 1e-12f);
    const float u = p0 / den;
    const float v = p1 / den;
    valid = (Z > 0.0f) & (u >= 0.0f) & (u < Ws) & (v >= 0.0f) & (v < Hs);
    const float us = u * sx;
    const float vs = v * sy;
    int px = (int)(us / 14.0f);
    int py = (int)(vs / 14.0f);
    px = px < 0 ? 0 : (px > 36 ? 36 : px);
    py = py < 0 ? 0 : (py > 36 ? 36 : py);
    flat = py*37 + px;
}

// Merged prepack: W1 (448x256), W2 (256x64), W3 (64x16) -> fragment-ordered bf16.
__global__ __launch_bounds__(256) void pack_all(
    const float* __restrict__ W1, const float* __restrict__ W2,
    const float* __restrict__ W3,
    unsigned short* __restrict__ o1, unsigned short* __restrict__ o2,
    unsigned short* __restrict__ o3)
{
    const int blk = blockIdx.x;
    if (blk < 448) {              // W1
        const int t = blk*256 + threadIdx.x;          // < 448*256
        const int k = t >> 8, n = t & 255;
        const int kc = k >> 5, g = (k >> 3) & 3, i = k & 7;
        const int w = n >> 6, nf = (n >> 4) & 3, m = n & 15;
        o1[(((kc*16 + w*4 + nf)*64 + g*16 + m) << 3) + i] = f2bf(W1[k*256 + n]);
    } else if (blk < 512) {       // W2
        const int t = (blk - 448)*256 + threadIdx.x;  // < 256*64
        const int k = t >> 6, n = t & 63;
        const int kc = k >> 5, g = (k >> 3) & 3, i = k & 7;
        const int nf = n >> 4, m = n & 15;
        o2[(((kc*4 + nf)*64 + g*16 + m) << 3) + i] = f2bf(W2[k*64 + n]);
    } else {                      // W3
        const int t = (blk - 512)*256 + threadIdx.x;  // < 64*16
        const int k = t >> 4, n = t & 15;
        const int kc = k >> 5, g = (k >> 3) & 3, i = k & 7;
        o3[((kc*64 + g*16 + n) << 3) + i] = f2bf(W3[k*16 + n]);
    }
}

// ptok: T[t][n] = bf16( patch[t][:] @ W1[64:448][n] ) for all 16428 tokens.
// LDS-staged coalesced patch loads (verified r13: -10us vs strided).
__global__ __launch_bounds__(256) void ptok_kernel(
    const float* __restrict__ patch,
    const unsigned short* __restrict__ w1p_,
    unsigned short* __restrict__ T)
{
    __shared__ __align__(16) unsigned short sA[32*408];

    const int tid  = threadIdx.x;
    const int lane = tid & 63;
    const int w    = __builtin_amdgcn_readfirstlane(tid >> 6);  // wave-uniform -> SGPR
    const int mrow = lane & 15;
    const int kg   = lane >> 4;
    const int rbase = blockIdx.x * 32;

    unsigned* sA32 = (unsigned*)sA;
    #pragma unroll
    for (int i = 0; i < 8; ++i) {
        const int r = w + 4*i;
        int row = rbase + r;
        row = row < NT ? row : NT - 1;
        const float2* src = (const float2*)(patch + (size_t)row*ND);
        #pragma unroll
        for (int c = 0; c < 3; ++c) {
            const float2 v = src[c*64 + lane];
            sA32[r*204 + c*64 + lane] = pack2bf(v.x, v.y);
        }
    }
    __syncthreads();

    const bf8_t* w1p = (const bf8_t*)w1p_;
    const f4_t zero = {0.f, 0.f, 0.f, 0.f};
    f4_t acc[2][4];
    #pragma unroll
    for (int a = 0; a < 2; ++a)
        #pragma unroll
        for (int q = 0; q < 4; ++q) acc[a][q] = zero;

    for (int j = 0; j < 12; ++j) {
        const bf8_t a0 = *(const bf8_t*)&sA[ mrow      *408 + j*32 + kg*8];
        const bf8_t a1 = *(const bf8_t*)&sA[(mrow + 16)*408 + j*32 + kg*8];
        const bf8_t* bp = w1p + (size_t)(((j+2)*16 + w*4)*64 + lane);
        #pragma unroll
        for (int nf = 0; nf < 4; ++nf) {
            const bf8_t bfr = bp[nf*64];
            acc[0][nf] = __builtin_amdgcn_mfma_f32_16x16x32_bf16(a0, bfr, acc[0][nf], 0, 0, 0);
            acc[1][nf] = __builtin_amdgcn_mfma_f32_16x16x32_bf16(a1, bfr, acc[1][nf], 0, 0, 0);
        }
    }
    #pragma unroll
    for (int nf = 0; nf < 4; ++nf)
        #pragma unroll
        for (int mf = 0; mf < 2; ++mf)
            #pragma unroll
            for (int r = 0; r < 4; ++r) {
                const int trow = rbase + mf*16 + kg*4 + r;
                if (trow < NT)
                    T[(size_t)trow*256 + w*64 + nf*16 + mrow] = f2bf(acc[mf][nf][r]);
            }
}

// Fused: A1 projection -> miniGEMM -> A2 paired gather (scalar addressing,
// branch-skipped loads, packed float2 accumulation, cselect reciprocal)
// -> GEMM2 -> GEMM3.
// LDS: sVP 16,896B + sVF 4,608B + sFlat 768B = 22,272B -> 7 blocks/CU.
__global__ __launch_bounds__(256, 7) void fuse_mlp_kernel(
    const float* __restrict__ vfeat,   // (B,V,F)
    const float* __restrict__ vcoord,  // (B,V,3)
    const float* __restrict__ imsz,    // (B,2)
    const float* __restrict__ intr,    // (B,C,3,3)
    const float* __restrict__ extr,    // (B,C,4,4)
    const float* __restrict__ b1,
    const float* __restrict__ b2,
    const float* __restrict__ b3,
    const unsigned short* __restrict__ w1p_,  // packed bf16 W1 (kc 0..1 used)
    const unsigned short* __restrict__ w2p_,
    const unsigned short* __restrict__ w3p_,
    const unsigned short* __restrict__ T,     // (16428,256) bf16
    float* __restrict__ scores)        // ws: (B*V,16)
{
    __shared__ __align__(16) unsigned short sVP[TILE*264];  // vpart+b1, then h1 bf16
    __shared__ __align__(16) unsigned short sVF[TILE*72];   // vfeat bf16; later h2 bf16
    __shared__ int sFlat[NC*TILE];

    const int tid  = threadIdx.x;
    const int base = blockIdx.x * TILE;
    const int lane = tid & 63;
    const int w    = __builtin_amdgcn_readfirstlane(tid >> 6);  // wave-uniform -> SGPR
    const int mrow = lane & 15;
    const int kg   = lane >> 4;

    // ---------- load vfeat -> sVF bf16 (float2-vectorized, coalesced) ----------
    #pragma unroll
    for (int i = 0; i < 4; ++i) {
        const int e = tid + 256*i;          // < 1024 float2 elements
        const int r = e >> 5, c2 = e & 31;
        const float2 v = *(const float2*)&vfeat[(size_t)(base + r)*NF + c2*2];
        *(unsigned*)&sVF[r*72 + c2*2] = pack2bf(v.x, v.y);
    }

    // ---------- A1: pair-parallel projection ----------
    if (tid < NC*TILE) {
        const int r = tid & 31, c = tid >> 5;
        const int n = base + r;
        const int b = n / NV;
        const float x = vcoord[(size_t)n*3+0];
        const float y = vcoord[(size_t)n*3+1];
        const float z = vcoord[(size_t)n*3+2];
        const float Hs = imsz[b*2+0];
        const float Ws = imsz[b*2+1];
        const float sx = 518.0f / fmaxf(Ws, 1e-6f);
        const float sy = 518.0f / fmaxf(Hs, 1e-6f);
        const float* E  = extr + (size_t)(b*NC + c)*16;
        const float* Km = intr + (size_t)(b*NC + c)*9;
        bool valid; int flat;
        proj_one(E, Km, x, y, z, Ws, Hs, sx, sy, valid, flat);
        sFlat[c*TILE + r] = valid ? flat : -1;
    }
    __syncthreads();

    // ---------- miniGEMM: vpart = vfeat(32x64) @ W1a(64x256) + b1 (NO relu) ----------
    const bf8_t* w1p = (const bf8_t*)w1p_;
    const f4_t zero = {0.f, 0.f, 0.f, 0.f};
    f4_t acc1[2][4];
    #pragma unroll
    for (int a = 0; a < 2; ++a)
        #pragma unroll
        for (int q = 0; q < 4; ++q) acc1[a][q] = zero;
    #pragma unroll
    for (int kc = 0; kc < 2; ++kc) {
        const bf8_t a0 = *(const bf8_t*)&sVF[ mrow      *72 + kc*32 + kg*8];
        const bf8_t a1 = *(const bf8_t*)&sVF[(mrow + 16)*72 + kc*32 + kg*8];
        const bf8_t* bp = w1p + (size_t)((kc*16 + w*4)*64 + lane);
        #pragma unroll
        for (int nf = 0; nf < 4; ++nf) {
            const bf8_t bfr = bp[nf*64];
            acc1[0][nf] = __builtin_amdgcn_mfma_f32_16x16x32_bf16(a0, bfr, acc1[0][nf], 0, 0, 0);
            acc1[1][nf] = __builtin_amdgcn_mfma_f32_16x16x32_bf16(a1, bfr, acc1[1][nf], 0, 0, 0);
        }
    }
    #pragma unroll
    for (int nf = 0; nf < 4; ++nf) {
        const float bb = b1[w*64 + nf*16 + mrow];
        #pragma unroll
        for (int mf = 0; mf < 2; ++mf)
            #pragma unroll
            for (int r = 0; r < 4; ++r)
                sVP[(mf*16 + kg*4 + r)*264 + w*64 + nf*16 + mrow] = f2bf(acc1[mf][nf][r] + bb);
    }
    __syncthreads();

    // ---------- A2: paired gather, scalar addressing, packed accumulation ----------
    #pragma unroll
    for (int t4 = 0; t4 < 4; ++t4) {
        const int r0 = w + 8*t4, r1 = r0 + 4;                 // SGPR
        const int cb0 = ((base + r0) / NV) * NC;              // SGPR
        const int cb1 = ((base + r1) / NV) * NC;
        float2 Ax = {0.f,0.f}, Ay = {0.f,0.f}; int cnt0 = 0;
        float2 Bx = {0.f,0.f}, By = {0.f,0.f}; int cnt1 = 0;
        #pragma unroll
        for (int c = 0; c < NC; ++c) {
            const int f0 = __builtin_amdgcn_readfirstlane(sFlat[c*TILE + r0]);
            const int f1 = __builtin_amdgcn_readfirstlane(sFlat[c*TILE + r1]);
            if (f0 >= 0) {    // scalar branch: s_cmp + s_cbranch
                const unsigned short* rp = T + ((size_t)(cb0 + c)*NM + f0)*256;
                const uint2 u = *(const uint2*)(rp + lane*4);  // saddr + shared voffset
                Ax.x += bflo(u.x); Ax.y += bfhi(u.x);          // pairable -> v_pk_add_f32
                Ay.x += bflo(u.y); Ay.y += bfhi(u.y);
                ++cnt0;
            }
            if (f1 >= 0) {
                const unsigned short* rp = T + ((size_t)(cb1 + c)*NM + f1)*256;
                const uint2 u = *(const uint2*)(rp + lane*4);
                Bx.x += bflo(u.x); Bx.y += bfhi(u.x);
                By.x += bflo(u.y); By.y += bfhi(u.y);
                ++cnt1;
            }
        }
        const float inv0 = inv_cnt(cnt0);   // scalar cselect chain, bit-exact
        const float inv1 = inv_cnt(cnt1);
        {
            const uint2 vp = *(uint2*)&sVP[r0*264 + lane*4];
            const float h0 = fmaxf(Ax.x*inv0 + bflo(vp.x), 0.f);
            const float h1v = fmaxf(Ax.y*inv0 + bfhi(vp.x), 0.f);
            const float h2v = fmaxf(Ay.x*inv0 + bflo(vp.y), 0.f);
            const float h3 = fmaxf(Ay.y*inv0 + bfhi(vp.y), 0.f);
            uint2 o; o.x = pack2bf(h0, h1v); o.y = pack2bf(h2v, h3);
            *(uint2*)&sVP[r0*264 + lane*4] = o;
        }
        {
            const uint2 vp = *(uint2*)&sVP[r1*264 + lane*4];
            const float h0 = fmaxf(Bx.x*inv1 + bflo(vp.x), 0.f);
            const float h1v = fmaxf(Bx.y*inv1 + bfhi(vp.x), 0.f);
            const float h2v = fmaxf(By.x*inv1 + bflo(vp.y), 0.f);
            const float h3 = fmaxf(By.y*inv1 + bfhi(vp.y), 0.f);
            uint2 o; o.x = pack2bf(h0, h1v); o.y = pack2bf(h2v, h3);
            *(uint2*)&sVP[r1*264 + lane*4] = o;
        }
    }
    __syncthreads();

    // ---------- GEMM2 (MFMA): h2 = relu(h1(32x256) @ W2(256x64) + b2) ----------
    unsigned short* sH1 = sVP;
    unsigned short* sH2bf = sVF;     // overlay (sVF dead after miniGEMM)
    const bf8_t* w2p = (const bf8_t*)w2p_;
    f4_t acc2[2];
    acc2[0] = zero; acc2[1] = zero;
    for (int kc = 0; kc < 8; ++kc) {
        const bf8_t a0 = *(const bf8_t*)&sH1[ mrow      *264 + kc*32 + kg*8];
        const bf8_t a1 = *(const bf8_t*)&sH1[(mrow + 16)*264 + kc*32 + kg*8];
        const bf8_t bfr = w2p[(kc*4 + w)*64 + lane];
        acc2[0] = __builtin_amdgcn_mfma_f32_16x16x32_bf16(a0, bfr, acc2[0], 0, 0, 0);
        acc2[1] = __builtin_amdgcn_mfma_f32_16x16x32_bf16(a1, bfr, acc2[1], 0, 0, 0);
    }
    {
        const float bb = b2[w*16 + mrow];
        #pragma unroll
        for (int mf = 0; mf < 2; ++mf)
            #pragma unroll
            for (int r = 0; r < 4; ++r) {
                const float v = fmaxf(acc2[mf][r] + bb, 0.f);
                sH2bf[(mf*16 + kg*4 + r)*72 + w*16 + mrow] = f2bf(v);
            }
    }
    __syncthreads();

    // ---------- GEMM3 (MFMA, waves 0-1): scores = h2(32x64) @ W3(64x16) + b3 ----------
    if (w < 2) {
        const bf8_t* w3p = (const bf8_t*)w3p_;
        f4_t acc3 = zero;
        #pragma unroll
        for (int kc = 0; kc < 2; ++kc) {
            const bf8_t a = *(const bf8_t*)&sH2bf[(w*16 + mrow)*72 + kc*32 + kg*8];
            const bf8_t bfr = w3p[kc*64 + lane];
            acc3 = __builtin_amdgcn_mfma_f32_16x16x32_bf16(a, bfr, acc3, 0, 0, 0);
        }
        const float bb = b3[mrow];
        #pragma unroll
        for (int r = 0; r < 4; ++r)
            scores[(size_t)(base + w*16 + kg*4 + r)*16 + mrow] = acc3[r] + bb;
    }
}

// out[b,p,:] = scores[b*V + idx[b,p], :]
__global__ __launch_bounds__(256) void gather_kernel(
    const float* __restrict__ scores,
    const int* __restrict__ p2v,
    float* __restrict__ out)
{
    const int g  = blockIdx.x * 256 + threadIdx.x;  // < 800000
    const int q  = g & 3;
    const int pl = g >> 2;
    const int b  = pl / NP;
    const int idx = p2v[pl];
    const float4 val = *(const float4*)&scores[((size_t)(b*NV + idx))*16 + q*4];
    *(float4*)&out[(size_t)g*4] = val;
}

extern "C" void kernel_launch(void* const* d_in, const int* in_sizes, int n_in,
                              void* d_out, int out_size, void* d_ws, size_t ws_size,
                              hipStream_t stream) {
    const float* patch = (const float*)d_in[0];
    const float* vfeat = (const float*)d_in[1];
    const float* vcoord= (const float*)d_in[2];
    const float* imsz  = (const float*)d_in[3];
    const float* intr  = (const float*)d_in[4];
    const float* extr  = (const float*)d_in[5];
    const int*   p2v   = (const int*)d_in[6];
    const float* W1 = (const float*)d_in[7];
    const float* b1 = (const float*)d_in[8];
    const float* W2 = (const float*)d_in[9];
    const float* b2 = (const float*)d_in[10];
    const float* W3 = (const float*)d_in[11];
    const float* b3 = (const float*)d_in[12];

    float* scores = (float*)d_ws;                                        // 6,400,000 B
    unsigned short* w1pack = (unsigned short*)((char*)d_ws + 6400000);   // 229,376 B
    unsigned short* w2pack = (unsigned short*)((char*)d_ws + 6629376);   // 32,768 B
    unsigned short* w3pack = (unsigned short*)((char*)d_ws + 6662144);   // 2,048 B
    unsigned short* Tbuf   = (unsigned short*)((char*)d_ws + 6664192);   // 8,411,136 B

    pack_all<<<516, 256, 0, stream>>>(W1, W2, W3, w1pack, w2pack, w3pack);
    ptok_kernel<<<(NT + 31)/32, 256, 0, stream>>>(patch, w1pack, Tbuf);
    fuse_mlp_kernel<<<NROW/TILE, 256, 0, stream>>>(
        vfeat, vcoord, imsz, intr, extr,
        b1, b2, b3, w1pack, w2pack, w3pack, Tbuf, scores);
    gather_kernel<<<(NB*NP*4)/256, 256, 0, stream>>>(scores, p2v, (float*)d_out);
}